// Round 1
// baseline (56.666 us; speedup 1.0000x reference)
//
#include <hip/hip_runtime.h>
#include <hip/hip_bf16.h>
#include <math.h>

#define BN 8
#define TT 128
#define DD 400
#define HH 300
#define LL 45

// ---------------- Kernel A: projections ----------------
// AP[row][h] = sum_d cont[row][d]*W1a[d][h] + b1[h]   (row = b*T+t, 1024 rows)
// BP[row][h] = sum_d cont[row][d]*W1b[d][h]
// RP[h]      = sum_d root[d]*W1b[d][h]
// grid: 256 blocks of 4 rows + 1 root block. block = 320 threads (thread h<300 active).
__global__ __launch_bounds__(320) void proj_kernel(
    const float* __restrict__ cont, const float* __restrict__ root,
    const float* __restrict__ W1a, const float* __restrict__ W1b,
    const float* __restrict__ b1,
    float* __restrict__ AP, float* __restrict__ BP, float* __restrict__ RP,
    float* __restrict__ accum)
{
    __shared__ float tile[4][DD];
    const int blk = blockIdx.x;
    const bool is_root = (blk == 256);
    const int row0 = blk * 4;
    const float* src = is_root ? root : cont + (size_t)row0 * DD;
    const int nel = is_root ? DD : 4 * DD;
    for (int i = threadIdx.x; i < nel; i += 320)
        tile[i / DD][i % DD] = src[i];
    __syncthreads();

    const int h = threadIdx.x;
    if (h >= HH) return;

    if (is_root) {
        if (h == 0) accum[0] = 0.f;   // zero the loss accumulator for this call
        float acc = 0.f;
        for (int d = 0; d < DD; d += 4) {
            #pragma unroll
            for (int k = 0; k < 4; ++k)
                acc = fmaf(tile[0][d + k], W1b[(d + k) * HH + h], acc);
        }
        RP[h] = acc;
    } else {
        float acca[4], accb[4];
        const float bb = b1[h];
        #pragma unroll
        for (int r = 0; r < 4; ++r) { acca[r] = bb; accb[r] = 0.f; }
        for (int d = 0; d < DD; d += 4) {
            float wa[4], wb[4];
            #pragma unroll
            for (int k = 0; k < 4; ++k) {
                wa[k] = W1a[(d + k) * HH + h];
                wb[k] = W1b[(d + k) * HH + h];
            }
            #pragma unroll
            for (int r = 0; r < 4; ++r) {
                #pragma unroll
                for (int k = 0; k < 4; ++k) {
                    const float v = tile[r][d + k];
                    acca[r] = fmaf(v, wa[k], acca[r]);
                    accb[r] = fmaf(v, wb[k], accb[r]);
                }
            }
        }
        #pragma unroll
        for (int r = 0; r < 4; ++r) {
            AP[(size_t)(row0 + r) * HH + h] = acca[r];
            BP[(size_t)(row0 + r) * HH + h] = accb[r];
        }
    }
}

// ---------------- Kernel B: per-(b,t) scoring ----------------
// grid = 1024 = B*T, block = 256 (4 waves). Early-exit when t >= len[b].
__global__ __launch_bounds__(256) void score_kernel(
    const float* __restrict__ AP, const float* __restrict__ BP,
    const float* __restrict__ RP,
    const float* __restrict__ Wa, const float* __restrict__ Wl,
    const float* __restrict__ bl,
    const int* __restrict__ slen, const int* __restrict__ des_arcs,
    const int* __restrict__ des_labels, const int* __restrict__ use_des,
    float* __restrict__ accum)
{
    const int blk = blockIdx.x;
    const int b = blk >> 7, t = blk & 127;
    const int len = slen[b];
    if (t >= len) return;

    const int tid = threadIdx.x;
    const int lane = tid & 63, wave = tid >> 6;

    __shared__ float logits[132];      // [0..128] arc logits, [129] stashes arc_ce
    __shared__ float selh[HH];
    __shared__ float lablg[LL];
    __shared__ int   sel_s;

    const float* ap = AP + (size_t)blk * HH;

    // Per-lane registers: fixed h-slice h = lane + 64*i
    float apr[5], war[5];
    #pragma unroll
    for (int i = 0; i < 5; ++i) {
        const int h = lane + 64 * i;
        const bool v = (h < HH);
        apr[i] = v ? ap[h] : 0.f;
        war[i] = v ? Wa[h] : 0.f;
    }

    // Arc logits: wave w handles s = w, w+4, ...
    for (int s = wave; s < TT + 1; s += 4) {
        const float* bp = (s == 0) ? RP : BP + (size_t)(b * TT + s - 1) * HH;
        float p = 0.f;
        #pragma unroll
        for (int i = 0; i < 5; ++i) {
            const int h = lane + 64 * i;
            const float bv = (h < HH) ? bp[h] : 0.f;
            float hv = apr[i] + bv;
            hv = fmaxf(hv, 0.f);
            p = fmaf(hv, war[i], p);
        }
        #pragma unroll
        for (int off = 32; off; off >>= 1) p += __shfl_xor(p, off, 64);
        if (lane == 0) logits[s] = p;
    }
    __syncthreads();

    // Softmax + argmax over 129 logits (wave 0)
    if (wave == 0) {
        const float v0 = logits[lane];
        const float v1 = logits[64 + lane];
        const float v2 = (lane == 0) ? logits[128] : -INFINITY;
        float m = fmaxf(fmaxf(v0, v1), v2);
        #pragma unroll
        for (int off = 32; off; off >>= 1) m = fmaxf(m, __shfl_xor(m, off, 64));
        float e = __expf(v0 - m) + __expf(v1 - m) + ((lane == 0) ? __expf(v2 - m) : 0.f);
        #pragma unroll
        for (int off = 32; off; off >>= 1) e += __shfl_xor(e, off, 64);
        const float lse = m + __logf(e);

        // argmax, ties -> lowest index (matches jnp.argmax)
        float bv = v0; int bi = lane;
        if (v1 > bv) { bv = v1; bi = 64 + lane; }
        if (lane == 0 && v2 > bv) { bv = v2; bi = 128; }
        #pragma unroll
        for (int off = 32; off; off >>= 1) {
            const float ov = __shfl_xor(bv, off, 64);
            const int   oi = __shfl_xor(bi, off, 64);
            if (ov > bv || (ov == bv && oi < bi)) { bv = ov; bi = oi; }
        }
        if (lane == 0) {
            const int da = des_arcs[b * TT + t];
            logits[129] = lse - logits[da];            // arc CE
            sel_s = use_des[0] ? da : bi;
        }
    }
    __syncthreads();

    // Selected pair representation -> label logits
    const int s = sel_s;
    const float* bp = (s == 0) ? RP : BP + (size_t)(b * TT + s - 1) * HH;
    for (int h = tid; h < HH; h += 256)
        selh[h] = fmaxf(ap[h] + bp[h], 0.f);
    __syncthreads();

    if (tid < LL) {
        float acc = bl[tid];
        for (int h = 0; h < HH; ++h)
            acc = fmaf(selh[h], Wl[h * LL + tid], acc);
        lablg[tid] = acc;
    }
    __syncthreads();

    if (wave == 0) {
        const float v = (lane < LL) ? lablg[lane] : -INFINITY;
        float m = v;
        #pragma unroll
        for (int off = 32; off; off >>= 1) m = fmaxf(m, __shfl_xor(m, off, 64));
        float e = (lane < LL) ? __expf(v - m) : 0.f;
        #pragma unroll
        for (int off = 32; off; off >>= 1) e += __shfl_xor(e, off, 64);
        const float lse = m + __logf(e);
        if (lane == 0) {
            const float lab_ce = lse - lablg[des_labels[b * TT + t]];
            atomicAdd(accum, logits[129] + lab_ce);
        }
    }
}

// ---------------- Kernel C: finalize ----------------
__global__ void finalize_kernel(const float* __restrict__ accum,
                                const int* __restrict__ slen,
                                float* __restrict__ out)
{
    if (threadIdx.x == 0) {
        int n = 0;
        for (int b = 0; b < BN; ++b) {
            int l = slen[b];
            if (l < 0) l = 0;
            if (l > TT) l = TT;
            n += l;
        }
        float nv = (float)n;
        if (nv < 1.f) nv = 1.f;
        out[0] = accum[0] / (2.f * nv);
    }
}

extern "C" void kernel_launch(void* const* d_in, const int* in_sizes, int n_in,
                              void* d_out, int out_size, void* d_ws, size_t ws_size,
                              hipStream_t stream) {
    const float* cont = (const float*)d_in[0];
    const float* root = (const float*)d_in[1];
    const float* W1a  = (const float*)d_in[2];
    const float* W1b  = (const float*)d_in[3];
    const float* b1   = (const float*)d_in[4];
    const float* Wa   = (const float*)d_in[5];
    // d_in[6] = ba: cancels in CE and argmax -> unused
    const float* Wl   = (const float*)d_in[7];
    const float* bl   = (const float*)d_in[8];
    const int* slen   = (const int*)d_in[9];
    const int* darc   = (const int*)d_in[10];
    const int* dlab   = (const int*)d_in[11];
    const int* used   = (const int*)d_in[12];
    float* out = (float*)d_out;

    float* AP    = (float*)d_ws;          // 1024*300
    float* BP    = AP + 1024 * HH;        // 1024*300
    float* RP    = BP + 1024 * HH;        // 320 (padded)
    float* accum = RP + 320;              // 1

    proj_kernel<<<257, 320, 0, stream>>>(cont, root, W1a, W1b, b1, AP, BP, RP, accum);
    score_kernel<<<1024, 256, 0, stream>>>(AP, BP, RP, Wa, Wl, bl, slen, darc, dlab, used, accum);
    finalize_kernel<<<1, 64, 0, stream>>>(accum, slen, out);
}

// Round 3
// 52.596 us; speedup vs baseline: 1.0774x; 1.0774x over previous
//
#include <hip/hip_runtime.h>
#include <hip/hip_bf16.h>
#include <math.h>

#define BN 8
#define TT 128
#define DD 400
#define HH 300
#define LL 45
#define KH 200   // K half per in-block K-group

// ---------------- Kernel A: projections ----------------
// grid = 257 blocks x 640 threads (10 waves).
//   blk <  128 : AP rows 8*blk..8*blk+7   (cont @ W1a + b1)
//   blk < 256  : BP rows 8*(blk-128)..    (cont @ W1b)
//   blk == 256 : RP = root @ W1b, and zero the loss accumulator
// Threads: grp = tid/320 takes K-half [grp*200, grp*200+200); h = tid%320 (active h<300).
// Row values are block-uniform -> scalar loads; weights coalesced per-lane.
// NOTE: BP rows must be computed for ALL t (head candidates are unmasked in the
// reference — log_softmax runs over every s in [0,T]). Only AP rows with
// t >= len[b] are dead (both CE terms and the label gather mask on t < len).
__global__ __launch_bounds__(640) void proj_kernel(
    const float* __restrict__ cont, const float* __restrict__ root,
    const float* __restrict__ W1a, const float* __restrict__ W1b,
    const float* __restrict__ b1,
    const int* __restrict__ slen,
    float* __restrict__ AP, float* __restrict__ BP, float* __restrict__ RP,
    float* __restrict__ accum)
{
    __shared__ float red[320][9];   // padded: lane h -> bank 9h%32, conflict-free
    const int blk = blockIdx.x;
    const int tid = threadIdx.x;
    const int grp = tid / 320;                       // wave-aligned (5 waves each)
    const int h   = tid % 320;
    const int d0  = __builtin_amdgcn_readfirstlane(grp * KH);  // force SGPR

    if (blk == 256) {
        if (tid == 0) accum[0] = 0.f;
        float acc = 0.f;
        if (h < HH) {
            const float* wp = W1b + (size_t)d0 * HH + h;
            for (int d = 0; d < KH; ++d)
                acc = fmaf(root[d0 + d], wp[(size_t)d * HH], acc);
        }
        if (grp == 1) red[h][0] = acc;
        __syncthreads();
        if (grp == 0 && h < HH) RP[h] = acc + red[h][0];
        return;
    }

    const bool isA = (blk < 128);
    const int rb   = isA ? blk : blk - 128;
    const int row0 = rb * 8;
    // Skip fully-masked row groups for AP ONLY (BP rows are head candidates
    // for every t and feed all arc softmax denominators).
    if (isA) {
        const int lenb = slen[row0 >> 7];
        if ((row0 & 127) >= lenb) return;
    }

    const float* W    = isA ? W1a : W1b;
    const float* rows = cont + (size_t)row0 * DD + d0;

    float acc[8];
    #pragma unroll
    for (int r = 0; r < 8; ++r) acc[r] = 0.f;

    if (h < HH) {
        const float* wp = W + (size_t)d0 * HH + h;
        float w[8];
        #pragma unroll
        for (int k = 0; k < 8; ++k) w[k] = wp[(size_t)k * HH];
        for (int dc = 0; dc < KH; dc += 8) {
            float wn[8];
            if (dc + 8 < KH) {
                #pragma unroll
                for (int k = 0; k < 8; ++k) wn[k] = wp[(size_t)(dc + 8 + k) * HH];
            } else {
                #pragma unroll
                for (int k = 0; k < 8; ++k) wn[k] = 0.f;
            }
            #pragma unroll
            for (int r = 0; r < 8; ++r) {
                const float* rp = rows + r * DD + dc;   // block-uniform -> s_load
                #pragma unroll
                for (int k = 0; k < 8; ++k)
                    acc[r] = fmaf(rp[k], w[k], acc[r]);
            }
            #pragma unroll
            for (int k = 0; k < 8; ++k) w[k] = wn[k];
        }
    }

    if (grp == 1) {
        #pragma unroll
        for (int r = 0; r < 8; ++r) red[h][r] = acc[r];
    }
    __syncthreads();
    if (grp == 0 && h < HH) {
        const float bb = isA ? b1[h] : 0.f;
        float* dst = (isA ? AP : BP) + (size_t)row0 * HH + h;
        #pragma unroll
        for (int r = 0; r < 8; ++r)
            dst[(size_t)r * HH] = acc[r] + red[h][r] + bb;
    }
}

// ---------------- Kernel B: per-(b, t-pair) scoring ----------------
// grid = 512 (= B * 64 t-pairs), block = 256 (4 waves). One BP stream feeds two t.
__global__ __launch_bounds__(256) void score_kernel(
    const float* __restrict__ AP, const float* __restrict__ BP,
    const float* __restrict__ RP,
    const float* __restrict__ Wa, const float* __restrict__ Wl,
    const float* __restrict__ bl,
    const int* __restrict__ slen, const int* __restrict__ des_arcs,
    const int* __restrict__ des_labels, const int* __restrict__ use_des,
    float* __restrict__ accum)
{
    const int blk = blockIdx.x;
    const int b = blk >> 6, tp = blk & 63;
    const int t0 = tp * 2, t1 = t0 + 1;
    const int len = slen[b];
    if (t0 >= len) return;
    const bool act1 = (t1 < len);

    const int tid = threadIdx.x;
    const int lane = tid & 63, wave = tid >> 6;

    __shared__ float logits[2][132];   // [.][0..128] arc logits, [.][129] arc CE
    __shared__ float selh[2][HH];
    __shared__ float lablg[2][64];
    __shared__ int   sel_s[2];

    const float* ap0 = AP + (size_t)(b * TT + t0) * HH;
    const float* ap1 = ap0 + HH;

    float apr0[5], apr1[5], war[5];
    #pragma unroll
    for (int i = 0; i < 5; ++i) {
        const int h = lane + 64 * i;
        const bool v = (h < HH);
        apr0[i] = v ? ap0[h] : 0.f;
        apr1[i] = v ? ap1[h] : 0.f;
        war[i]  = v ? Wa[h]  : 0.f;
    }

    // Arc logits for both t, sharing the bp stream. wave w: s = w, w+4, ...
    for (int s = wave; s < TT + 1; s += 4) {
        const float* bp = (s == 0) ? RP : BP + (size_t)(b * TT + s - 1) * HH;
        float p0 = 0.f, p1 = 0.f;
        #pragma unroll
        for (int i = 0; i < 5; ++i) {
            const int h = lane + 64 * i;
            const float bv = (h < HH) ? bp[h] : 0.f;
            p0 = fmaf(fmaxf(apr0[i] + bv, 0.f), war[i], p0);
            p1 = fmaf(fmaxf(apr1[i] + bv, 0.f), war[i], p1);
        }
        #pragma unroll
        for (int off = 32; off; off >>= 1) {
            p0 += __shfl_xor(p0, off, 64);
            p1 += __shfl_xor(p1, off, 64);
        }
        if (lane == 0) { logits[0][s] = p0; logits[1][s] = p1; }
    }
    __syncthreads();

    // Softmax + argmax over 129 logits: wave 0 -> t0, wave 1 -> t1
    if (wave < 2) {
        const int tt = wave ? t1 : t0;
        const float* lg = logits[wave];
        const float v0 = lg[lane];
        const float v1 = lg[64 + lane];
        const float v2 = (lane == 0) ? lg[128] : -INFINITY;
        float m = fmaxf(fmaxf(v0, v1), v2);
        #pragma unroll
        for (int off = 32; off; off >>= 1) m = fmaxf(m, __shfl_xor(m, off, 64));
        float e = __expf(v0 - m) + __expf(v1 - m) + ((lane == 0) ? __expf(v2 - m) : 0.f);
        #pragma unroll
        for (int off = 32; off; off >>= 1) e += __shfl_xor(e, off, 64);
        const float lse = m + __logf(e);

        float bv = v0; int bi = lane;
        if (v1 > bv) { bv = v1; bi = 64 + lane; }
        if (lane == 0 && v2 > bv) { bv = v2; bi = 128; }
        #pragma unroll
        for (int off = 32; off; off >>= 1) {
            const float ov = __shfl_xor(bv, off, 64);
            const int   oi = __shfl_xor(bi, off, 64);
            if (ov > bv || (ov == bv && oi < bi)) { bv = ov; bi = oi; }
        }
        if (lane == 0) {
            const int da = des_arcs[b * TT + tt];
            logits[wave][129] = lse - lg[da];          // arc CE
            sel_s[wave] = use_des[0] ? da : bi;
        }
    }
    __syncthreads();

    // Selected pair representations for both t
    for (int j = tid; j < 2 * HH; j += 256) {
        const int w2 = (j < HH) ? 0 : 1;
        const int h  = j - w2 * HH;
        const int s  = sel_s[w2];
        const float* bp = (s == 0) ? RP : BP + (size_t)(b * TT + s - 1) * HH;
        const float* ap = w2 ? ap1 : ap0;
        selh[w2][h] = fmaxf(ap[h] + bp[h], 0.f);
    }
    __syncthreads();

    // Label logits: wave 0 -> t0, wave 1 -> t1
    if (wave < 2 && lane < LL) {
        float a = bl[lane];
        for (int h = 0; h < HH; ++h)
            a = fmaf(selh[wave][h], Wl[h * LL + lane], a);
        lablg[wave][lane] = a;
    }
    __syncthreads();

    if (wave < 2) {
        const int tt = wave ? t1 : t0;
        const float v = (lane < LL) ? lablg[wave][lane] : -INFINITY;
        float m = v;
        #pragma unroll
        for (int off = 32; off; off >>= 1) m = fmaxf(m, __shfl_xor(m, off, 64));
        float e = (lane < LL) ? __expf(v - m) : 0.f;
        #pragma unroll
        for (int off = 32; off; off >>= 1) e += __shfl_xor(e, off, 64);
        const float lse = m + __logf(e);
        if (lane == 0 && (wave == 0 || act1)) {
            const float lab_ce = lse - lablg[wave][des_labels[b * TT + tt]];
            atomicAdd(accum, logits[wave][129] + lab_ce);
        }
    }
}

// ---------------- Kernel C: finalize ----------------
__global__ void finalize_kernel(const float* __restrict__ accum,
                                const int* __restrict__ slen,
                                float* __restrict__ out)
{
    if (threadIdx.x == 0) {
        int n = 0;
        for (int b = 0; b < BN; ++b) {
            int l = slen[b];
            if (l < 0) l = 0;
            if (l > TT) l = TT;
            n += l;
        }
        float nv = (float)n;
        if (nv < 1.f) nv = 1.f;
        out[0] = accum[0] / (2.f * nv);
    }
}

extern "C" void kernel_launch(void* const* d_in, const int* in_sizes, int n_in,
                              void* d_out, int out_size, void* d_ws, size_t ws_size,
                              hipStream_t stream) {
    const float* cont = (const float*)d_in[0];
    const float* root = (const float*)d_in[1];
    const float* W1a  = (const float*)d_in[2];
    const float* W1b  = (const float*)d_in[3];
    const float* b1   = (const float*)d_in[4];
    const float* Wa   = (const float*)d_in[5];
    // d_in[6] = ba: cancels in CE and argmax -> unused
    const float* Wl   = (const float*)d_in[7];
    const float* bl   = (const float*)d_in[8];
    const int* slen   = (const int*)d_in[9];
    const int* darc   = (const int*)d_in[10];
    const int* dlab   = (const int*)d_in[11];
    const int* used   = (const int*)d_in[12];
    float* out = (float*)d_out;

    float* AP    = (float*)d_ws;          // 1024*300
    float* BP    = AP + 1024 * HH;        // 1024*300
    float* RP    = BP + 1024 * HH;        // 320 (padded)
    float* accum = RP + 320;              // 1

    proj_kernel<<<257, 640, 0, stream>>>(cont, root, W1a, W1b, b1, slen, AP, BP, RP, accum);
    score_kernel<<<512, 256, 0, stream>>>(AP, BP, RP, Wa, Wl, bl, slen, darc, dlab, used, accum);
    finalize_kernel<<<1, 64, 0, stream>>>(accum, slen, out);
}

// Round 8
// 44.986 us; speedup vs baseline: 1.2596x; 1.1692x over previous
//
#include <hip/hip_runtime.h>
#include <hip/hip_bf16.h>
#include <math.h>

#define BN 8
#define TT 128
#define DD 400
#define HH 300
#define LL 45
#define KH 200          // K half per in-block K-group (proj)
#define SS 129          // T+1 head candidates
#define ALG_STRIDE 132  // padded logit row

// ---------------- Kernel A: projections ----------------
// grid = 257 blocks x 640 threads (10 waves).
//   blk <  128 : AP rows 8*blk..8*blk+7            (cont @ W1a + b1)
//   blk <  256 : BPX[b][t+1] rows for 8 t          (cont @ W1b)
//   blk == 256 : BPX[b][0] = root @ W1b for all b; zero accum
// BPX rows exist for ALL t (head candidates are unmasked in the reference);
// only AP rows with t >= len[b] are dead (CE terms & label gather mask t<len).
__global__ __launch_bounds__(640) void proj_kernel(
    const float* __restrict__ cont, const float* __restrict__ root,
    const float* __restrict__ W1a, const float* __restrict__ W1b,
    const float* __restrict__ b1,
    const int* __restrict__ slen,
    float* __restrict__ AP, float* __restrict__ BPX,
    float* __restrict__ accum)
{
    __shared__ float red[320][9];   // padded: conflict-free column access
    const int blk = blockIdx.x;
    const int tid = threadIdx.x;
    const int grp = tid / 320;                       // wave-aligned K-group
    const int h   = tid % 320;
    const int d0  = __builtin_amdgcn_readfirstlane(grp * KH);

    if (blk == 256) {
        if (tid == 0) accum[0] = 0.f;
        float acc = 0.f;
        if (h < HH) {
            const float* wp = W1b + (size_t)d0 * HH + h;
            for (int d = 0; d < KH; ++d)
                acc = fmaf(root[d0 + d], wp[(size_t)d * HH], acc);
        }
        if (grp == 1) red[h][0] = acc;
        __syncthreads();
        if (grp == 0 && h < HH) {
            const float v = acc + red[h][0];
            for (int bb = 0; bb < BN; ++bb)
                BPX[(size_t)bb * SS * HH + h] = v;   // root row per batch
        }
        return;
    }

    const bool isA = (blk < 128);
    const int rb   = isA ? blk : blk - 128;
    const int row0 = rb * 8;
    if (isA) {  // skip fully-masked AP row groups only
        const int lenb = slen[row0 >> 7];
        if ((row0 & 127) >= lenb) return;
    }

    const float* W    = isA ? W1a : W1b;
    const float* rows = cont + (size_t)row0 * DD + d0;

    float acc[8];
    #pragma unroll
    for (int r = 0; r < 8; ++r) acc[r] = 0.f;

    if (h < HH) {
        const float* wp = W + (size_t)d0 * HH + h;
        float w[8];
        #pragma unroll
        for (int k = 0; k < 8; ++k) w[k] = wp[(size_t)k * HH];
        for (int dc = 0; dc < KH; dc += 8) {
            float wn[8];
            if (dc + 8 < KH) {
                #pragma unroll
                for (int k = 0; k < 8; ++k) wn[k] = wp[(size_t)(dc + 8 + k) * HH];
            } else {
                #pragma unroll
                for (int k = 0; k < 8; ++k) wn[k] = 0.f;
            }
            #pragma unroll
            for (int r = 0; r < 8; ++r) {
                const float* rp = rows + r * DD + dc;   // block-uniform -> s_load
                #pragma unroll
                for (int k = 0; k < 8; ++k)
                    acc[r] = fmaf(rp[k], w[k], acc[r]);
            }
            #pragma unroll
            for (int k = 0; k < 8; ++k) w[k] = wn[k];
        }
    }

    if (grp == 1) {
        #pragma unroll
        for (int r = 0; r < 8; ++r) red[h][r] = acc[r];
    }
    __syncthreads();
    if (grp == 0 && h < HH) {
        if (isA) {
            const float bb = b1[h];
            float* dst = AP + (size_t)row0 * HH + h;
            #pragma unroll
            for (int r = 0; r < 8; ++r)
                dst[(size_t)r * HH] = acc[r] + red[h][r] + bb;
        } else {
            const int b = row0 >> 7, t = row0 & 127;
            float* dst = BPX + ((size_t)(b * SS + t + 1)) * HH + h;
            #pragma unroll
            for (int r = 0; r < 8; ++r)
                dst[(size_t)r * HH] = acc[r] + red[h][r];
        }
    }
}

// ---------------- Kernel B1: arc logits ----------------
// grid = 2048: blk = b*256 + tg*8 + sc  (tg: 32 t-groups of 4, sc: 8 s-chunks of 17)
// block = 256 (4 waves); wave w handles s = sc*17 + w + 4k. Lanes over h.
__global__ __launch_bounds__(256) void arc_kernel(
    const float* __restrict__ AP, const float* __restrict__ BPX,
    const float* __restrict__ Wa, const int* __restrict__ slen,
    float* __restrict__ ALG)
{
    const int blk = blockIdx.x;
    const int b  = blk >> 8;
    const int tg = (blk >> 3) & 31;
    const int sc = blk & 7;
    const int t0 = tg * 4;
    if (t0 >= slen[b]) return;   // whole t-group masked; its ALG rows are never read

    const int lane = threadIdx.x & 63;
    const int wave = threadIdx.x >> 6;

    const float* ap = AP + (size_t)(b * TT + t0) * HH;
    float apr[4][5], war[5];
    #pragma unroll
    for (int i = 0; i < 5; ++i) {
        const int hh = lane + 64 * i;
        const bool v = (hh < HH);
        war[i] = v ? Wa[hh] : 0.f;
        #pragma unroll
        for (int r = 0; r < 4; ++r)
            apr[r][i] = v ? ap[(size_t)r * HH + hh] : 0.f;
    }

    const int s0 = sc * 17;
    for (int sl = wave; sl < 17; sl += 4) {
        const int s = s0 + sl;
        if (s >= SS) break;
        const float* bp = BPX + (size_t)(b * SS + s) * HH;
        float bv[5];
        #pragma unroll
        for (int i = 0; i < 5; ++i) {
            const int hh = lane + 64 * i;
            bv[i] = (hh < HH) ? bp[hh] : 0.f;
        }
        float p0 = 0.f, p1 = 0.f, p2 = 0.f, p3 = 0.f;
        #pragma unroll
        for (int i = 0; i < 5; ++i) {
            p0 = fmaf(fmaxf(apr[0][i] + bv[i], 0.f), war[i], p0);
            p1 = fmaf(fmaxf(apr[1][i] + bv[i], 0.f), war[i], p1);
            p2 = fmaf(fmaxf(apr[2][i] + bv[i], 0.f), war[i], p2);
            p3 = fmaf(fmaxf(apr[3][i] + bv[i], 0.f), war[i], p3);
        }
        #pragma unroll
        for (int off = 32; off; off >>= 1) {
            p0 += __shfl_xor(p0, off, 64);
            p1 += __shfl_xor(p1, off, 64);
            p2 += __shfl_xor(p2, off, 64);
            p3 += __shfl_xor(p3, off, 64);
        }
        if (lane == 0) {
            float* o = ALG + (size_t)(b * TT + t0) * ALG_STRIDE + s;
            o[0]              = p0;
            o[ALG_STRIDE]     = p1;
            o[2 * ALG_STRIDE] = p2;
            o[3 * ALG_STRIDE] = p3;
        }
    }
}

// ---------------- Kernel B2: softmax + CE + label ----------------
// grid = 1024 = B*T, one wave per (b,t).
__global__ __launch_bounds__(64) void smx_kernel(
    const float* __restrict__ AP, const float* __restrict__ BPX,
    const float* __restrict__ Wl, const float* __restrict__ bl,
    const float* __restrict__ ALG,
    const int* __restrict__ slen, const int* __restrict__ des_arcs,
    const int* __restrict__ des_labels, const int* __restrict__ use_des,
    float* __restrict__ accum)
{
    const int blk = blockIdx.x;
    const int b = blk >> 7, t = blk & 127;
    if (t >= slen[b]) return;
    const int lane = threadIdx.x;

    __shared__ float selh[HH];

    const float* lg = ALG + (size_t)blk * ALG_STRIDE;
    const float v0 = lg[lane];
    const float v1 = lg[64 + lane];
    const float v2 = (lane == 0) ? lg[128] : -INFINITY;

    float m = fmaxf(fmaxf(v0, v1), v2);
    #pragma unroll
    for (int off = 32; off; off >>= 1) m = fmaxf(m, __shfl_xor(m, off, 64));
    float e = __expf(v0 - m) + __expf(v1 - m) + ((lane == 0) ? __expf(v2 - m) : 0.f);
    #pragma unroll
    for (int off = 32; off; off >>= 1) e += __shfl_xor(e, off, 64);
    const float arc_lse = m + __logf(e);

    // argmax (ties -> lowest index), butterfly leaves result in all lanes
    float bv = v0; int bi = lane;
    if (v1 > bv) { bv = v1; bi = 64 + lane; }
    if (lane == 0 && v2 > bv) { bv = v2; bi = 128; }
    #pragma unroll
    for (int off = 32; off; off >>= 1) {
        const float ov = __shfl_xor(bv, off, 64);
        const int   oi = __shfl_xor(bi, off, 64);
        if (ov > bv || (ov == bv && oi < bi)) { bv = ov; bi = oi; }
    }

    const int da = des_arcs[b * TT + t];
    const float arc_ce = arc_lse - lg[da];
    const int sel = use_des[0] ? da : bi;

    // selected pair representation -> LDS
    const float* ap = AP + (size_t)blk * HH;
    const float* bp = BPX + (size_t)(b * SS + sel) * HH;
    #pragma unroll
    for (int i = 0; i < 5; ++i) {
        const int hh = lane + 64 * i;
        if (hh < HH) selh[hh] = fmaxf(ap[hh] + bp[hh], 0.f);
    }
    __syncthreads();

    // label logits: lane l < 45 owns output l; Wl reads coalesced per h
    float a = 0.f;
    if (lane < LL) {
        a = bl[lane];
        for (int hh = 0; hh < HH; hh += 4) {
            #pragma unroll
            for (int k = 0; k < 4; ++k)
                a = fmaf(selh[hh + k], Wl[(hh + k) * LL + lane], a);
        }
    }
    const float v = (lane < LL) ? a : -INFINITY;
    float lm = v;
    #pragma unroll
    for (int off = 32; off; off >>= 1) lm = fmaxf(lm, __shfl_xor(lm, off, 64));
    float le = (lane < LL) ? __expf(v - lm) : 0.f;
    #pragma unroll
    for (int off = 32; off; off >>= 1) le += __shfl_xor(le, off, 64);
    const float lab_lse = lm + __logf(le);

    const int dl = des_labels[b * TT + t];
    const float ldl = __shfl(v, dl, 64);
    if (lane == 0)
        atomicAdd(accum, arc_ce + (lab_lse - ldl));
}

// ---------------- Kernel C: finalize ----------------
__global__ void finalize_kernel(const float* __restrict__ accum,
                                const int* __restrict__ slen,
                                float* __restrict__ out)
{
    if (threadIdx.x == 0) {
        int n = 0;
        for (int b = 0; b < BN; ++b) {
            int l = slen[b];
            if (l < 0) l = 0;
            if (l > TT) l = TT;
            n += l;
        }
        float nv = (float)n;
        if (nv < 1.f) nv = 1.f;
        out[0] = accum[0] / (2.f * nv);
    }
}

extern "C" void kernel_launch(void* const* d_in, const int* in_sizes, int n_in,
                              void* d_out, int out_size, void* d_ws, size_t ws_size,
                              hipStream_t stream) {
    const float* cont = (const float*)d_in[0];
    const float* root = (const float*)d_in[1];
    const float* W1a  = (const float*)d_in[2];
    const float* W1b  = (const float*)d_in[3];
    const float* b1   = (const float*)d_in[4];
    const float* Wa   = (const float*)d_in[5];
    // d_in[6] = ba: cancels in CE and argmax -> unused
    const float* Wl   = (const float*)d_in[7];
    const float* bl   = (const float*)d_in[8];
    const int* slen   = (const int*)d_in[9];
    const int* darc   = (const int*)d_in[10];
    const int* dlab   = (const int*)d_in[11];
    const int* used   = (const int*)d_in[12];
    float* out = (float*)d_out;

    float* AP    = (float*)d_ws;              // 1024*300
    float* BPX   = AP  + 1024 * HH;           // 8*129*300
    float* ALG   = BPX + BN * SS * HH;        // 1024*132
    float* accum = ALG + 1024 * ALG_STRIDE;   // 1

    proj_kernel<<<257, 640, 0, stream>>>(cont, root, W1a, W1b, b1, slen, AP, BPX, accum);
    arc_kernel<<<2048, 256, 0, stream>>>(AP, BPX, Wa, slen, ALG);
    smx_kernel<<<1024, 64, 0, stream>>>(AP, BPX, Wl, bl, ALG, slen, darc, dlab, used, accum);
    finalize_kernel<<<1, 64, 0, stream>>>(accum, slen, out);
}